// Round 3
// baseline (245.259 us; speedup 1.0000x reference)
//
#include <hip/hip_runtime.h>

// IRFDeconv3D: out[b,p,t] = sum_{tau<=t} data[b,p,tau] * knorm[b,t-tau]
// == per-batch GEMM A[16384x256] @ Toeplitz(knorm)[256x256], keep n<256.
//
// v7: residency attack, round 2. v5/v6 both sat at ~35% occupancy / 86us:
// VGPR_Count (52-64) hid ~128 AGPRs of A-staging in the unified file ->
// 2.8 waves/SIMD, and BW tracked occupancy linearly (pure streaming).
// Changes:
//  - A staged via global_load_lds (zero register footprint, un-sinkable):
//    8 KiB slab double-buffered in LDS, SOURCE pre-swizzled (c^=row&7)
//    so ds_read_b128 row-slices are 2-way bank-aliased (free) not 16-way.
//  - Counted s_waitcnt vmcnt(2) + raw s_barrier per slab (T4): next-slab
//    DMA stays in flight across the barrier; only the 2 just-issued
//    stores remain outstanding.
//  - j-outer kept: acc = 2 live f32x4; af[8] (32 regs) accumulates bf16
//    slabs as they arrive. Total ~80-100 regs, LDS 32 KiB -> 5 blocks/CU
//    = 20 waves/CU (62.5%), ~2x v6 residency.

typedef __attribute__((ext_vector_type(8))) short short8;
typedef __attribute__((ext_vector_type(4))) float floatx4;

#define T_BINS 256
#define PIX_PER_B (128 * 128)

typedef __attribute__((address_space(3))) void lds_void;
typedef __attribute__((address_space(1))) const void gbl_void;

__device__ __forceinline__ void gload_lds16(const void* g, void* l) {
    __builtin_amdgcn_global_load_lds((gbl_void*)g, (lds_void*)l, 16, 0, 0);
}

__device__ inline unsigned short f2bf(float f) {
    unsigned int u = __float_as_uint(f);
    u += 0x7fffu + ((u >> 16) & 1u);   // round-to-nearest-even
    return (unsigned short)(u >> 16);
}

// Wd[b][d][n'][kl] (bf16) = knorm[16*d + n' - kl] if idx >= 0 else 0.
__global__ __launch_bounds__(256) void build_W(const float* __restrict__ irf,
                                               unsigned short* __restrict__ W) {
    __shared__ float red[256];
    __shared__ float knorm[256];
    const int b = blockIdx.x;
    const int t = threadIdx.x;
    float v = irf[b * T_BINS + t];
    red[t] = v;
    __syncthreads();
    for (int s = 128; s > 0; s >>= 1) {
        if (t < s) red[t] = fmaxf(red[t], red[t + s]);
        __syncthreads();
    }
    knorm[t] = v / red[0];
    __syncthreads();
    unsigned short* Wb = W + b * 8192;
#pragma unroll
    for (int i = 0; i < 32; i++) {
        int e = i * 256 + t;            // coalesced
        int d  = e >> 9;
        int np = (e >> 5) & 15;
        int kl = e & 31;
        int idx = 16 * d + np - kl;
        Wb[e] = (idx >= 0) ? f2bf(knorm[idx]) : (unsigned short)0;
    }
}

__device__ inline short8 cvt_a(float4 lo, float4 hi) {
    short8 a;
    a[0] = (short)f2bf(lo.x); a[1] = (short)f2bf(lo.y);
    a[2] = (short)f2bf(lo.z); a[3] = (short)f2bf(lo.w);
    a[4] = (short)f2bf(hi.x); a[5] = (short)f2bf(hi.y);
    a[6] = (short)f2bf(hi.z); a[7] = (short)f2bf(hi.w);
    return a;
}

__global__ __launch_bounds__(256, 5) void conv_gemm(const float* __restrict__ data,
                                                    const unsigned short* __restrict__ W,
                                                    float* __restrict__ out) {
    // LDS: [0,16K) B diag table; [16K,24K) A buf0; [24K,32K) A buf1
    __shared__ alignas(16) unsigned char ldsb[32768];
    unsigned short* Bs = (unsigned short*)ldsb;

    const int b = blockIdx.x >> 8;        // 256 m-tiles per batch
    const int mt = blockIdx.x & 255;
    const int t = threadIdx.x;
    const int w = t >> 6;                 // wave id (0..3)
    const int l = t & 63;
    const int lq = l >> 4;                // quad (0..3)
    const int lm = l & 15;

    // ---- DMA source addresses (pre-swizzled: LDS unit (r,c') holds global
    //      chunk c = c' ^ (r&7); each chunk is 16 B = 4 floats) ----
    const float* Ab = data + ((size_t)b * PIX_PER_B + mt * 64) * T_BINS;
    const int u0 = t,       r0 = u0 >> 3, c0 = (u0 & 7) ^ (r0 & 7);
    const int u1 = 256 + t, r1 = u1 >> 3, c1 = (u1 & 7) ^ (r1 & 7);
    const float* asrc0 = Ab + r0 * T_BINS + c0 * 4;   // + kk*32 per slab
    const float* asrc1 = Ab + r1 * T_BINS + c1 * 4;
    const int admaoff = w * 1024;         // wave-uniform LDS dest base part

    // ---- prologue: DMA slab 0 (2 instrs) + B table (4 instrs, linear) ----
    gload_lds16(asrc0, ldsb + 16384 + admaoff);
    gload_lds16(asrc1, ldsb + 16384 + 4096 + admaoff);
    const unsigned short* Wb = W + b * 8192;
#pragma unroll
    for (int i = 0; i < 4; i++)
        gload_lds16(Wb + (i * 256 + t) * 8, ldsb + i * 4096 + admaoff);
    __syncthreads();                      // drains vmcnt(0), full fence

    // ---- per-lane read addresses ----
    const int e = lm & 7;                 // (row & 7) for this lane's row
    const int rr = w * 16 + lm;           // lane's row within the 64-row tile
    const int a_off0 = (rr * 8 + ((2 * lq) ^ e)) * 16;      // chunk 2lq
    const int a_off1 = (rr * 8 + ((2 * lq + 1) ^ e)) * 16;  // chunk 2lq+1
    const unsigned short* BsLane = Bs + lm * 32 + lq * 8;
    float* Orow = out + ((size_t)b * PIX_PER_B + mt * 64 + rr) * T_BINS;

    short8 af[8];                         // bf16 A slabs, accumulated live

#pragma unroll
    for (int kk = 0; kk < 8; kk++) {
        // issue DMA for slab kk+1 into the other buffer
        if (kk < 7) {
            const float* s0 = asrc0 + (kk + 1) * 32;
            const float* s1 = asrc1 + (kk + 1) * 32;
            unsigned char* dd = ldsb + 16384 + (((kk + 1) & 1) ? 8192 : 0) + admaoff;
            gload_lds16(s0, dd);
            gload_lds16(s1, dd + 4096);
        }
        __builtin_amdgcn_sched_barrier(0);   // pin DMA issue before compute

        const unsigned char* abase = ldsb + 16384 + ((kk & 1) ? 8192 : 0);
        float4 lo = *(const float4*)(abase + a_off0);
        float4 hi = *(const float4*)(abase + a_off1);
        af[kk] = cvt_a(lo, hi);

        // tiles j = 2kk, 2kk+1 are complete after slab kk: finish + store
#pragma unroll
        for (int jo = 0; jo < 2; jo++) {
            const int j = 2 * kk + jo;
            floatx4 acc = (floatx4){0.f, 0.f, 0.f, 0.f};
#pragma unroll
            for (int k2 = 0; k2 <= kk; k2++) {
                const int d2 = j - 2 * k2;
                short8 bf = *(const short8*)(BsLane + d2 * 512);
                // swapped operands: computes the transposed tile
                acc = __builtin_amdgcn_mfma_f32_16x16x32_bf16(bf, af[k2],
                                                              acc, 0, 0, 0);
            }
            *reinterpret_cast<floatx4*>(Orow + 16 * j + 4 * lq) = acc;
        }
        __builtin_amdgcn_sched_barrier(0);   // keep the 2 stores inside the phase

        if (kk < 7) {
            // outstanding VMEM: 2 DMA (slab kk+1) then 2 stores. vmcnt(2)
            // -> DMA complete, stores still in flight (never drain to 0).
            asm volatile("s_waitcnt vmcnt(2)" ::: "memory");
            __builtin_amdgcn_s_barrier();
            __builtin_amdgcn_sched_barrier(0);  // no ds_read hoists above barrier
        }
    }
}

extern "C" void kernel_launch(void* const* d_in, const int* in_sizes, int n_in,
                              void* d_out, int out_size, void* d_ws, size_t ws_size,
                              hipStream_t stream) {
    const float* data = (const float*)d_in[0];   // [8,128,128,256,1] fp32
    const float* irf  = (const float*)d_in[1];   // [8,1,1,256,1] fp32
    float* outp = (float*)d_out;                 // [8,128,128,256,1] fp32
    unsigned short* W = (unsigned short*)d_ws;   // 8*16*16*32 bf16 = 128 KiB

    build_W<<<8, 256, 0, stream>>>(irf, W);
    conv_gemm<<<2048, 256, 0, stream>>>(data, W, outp);
}